// Round 14
// baseline (9553.086 us; speedup 1.0000x reference)
//
#include <hip/hip_runtime.h>
#include <hip/hip_bf16.h>
#include <math.h>

#define BATCH 128
#define NN 512
#define DD 128
#define D3 384
#define NEGV (-1.0e9f)
#define NEGINF (-1.0e30f)

// ---- k_fixed: graph mean -> fixed ctx; also q0 = fixed + Wph @ Wstep --------
__global__ __launch_bounds__(256) void k_fixed(const float* __restrict__ emb,
                                               const float* __restrict__ Wf,
                                               const float* __restrict__ Wstep,
                                               const float* __restrict__ Wph,
                                               float* __restrict__ fixedc,
                                               float* __restrict__ q0) {
  const int b = blockIdx.x;
  __shared__ float s_part[2][DD];
  __shared__ float s_ge[DD];
  const int tid = threadIdx.x;
  const int d = tid & 127, c = tid >> 7;
  const float* e = emb + (size_t)b * NN * DD;
  float acc = 0.f;
  for (int n = c * 256; n < c * 256 + 256; ++n) acc += e[(size_t)n * DD + d];
  s_part[c][d] = acc;
  __syncthreads();
  if (tid < DD) s_ge[tid] = (s_part[0][tid] + s_part[1][tid]) * (1.0f / 512.0f);
  __syncthreads();
  if (tid < DD) {
    float a = 0.f;
    for (int k = 0; k < DD; ++k) a += s_ge[k] * Wf[k * DD + tid];
    fixedc[b * DD + tid] = a;
    float pq = 0.f;
    for (int k = 0; k < 2 * DD; ++k) pq += Wph[k] * Wstep[k * DD + tid];
    q0[b * DD + tid] = a + pq;
  }
}

// ---- proj = emb @ W_node_proj : [B*N,128] x [128,384] -----------------------
__global__ __launch_bounds__(384) void k_proj(const float* __restrict__ emb,
                                              const float* __restrict__ Wp,
                                              float* __restrict__ proj) {
  const size_t row0 = (size_t)blockIdx.x * 32;
  __shared__ float s_A[32][DD];
  const int tid = threadIdx.x;  // 384
  for (int t = tid; t < 32 * DD; t += 384)
    s_A[t >> 7][t & 127] = emb[row0 * DD + t];
  __syncthreads();
  float acc[32];
#pragma unroll
  for (int r = 0; r < 32; ++r) acc[r] = 0.f;
  const int c = tid;
  for (int k = 0; k < DD; ++k) {
    float w = Wp[k * D3 + c];
#pragma unroll
    for (int r = 0; r < 32; ++r) acc[r] += s_A[r][k] * w;
  }
  for (int r = 0; r < 32; ++r) proj[(row0 + r) * D3 + c] = acc[r];
}

// ---- k_lp: in-place logit_K <- Wout @ logit_K per row -----------------------
__global__ __launch_bounds__(128) void k_lp(float* __restrict__ proj,
                                            const float* __restrict__ Wout) {
  const size_t row0 = (size_t)blockIdx.x * 32;
  __shared__ float s_L[32][DD];
  const int tid = threadIdx.x;  // 128
  for (int rr = 0; rr < 32; ++rr)
    s_L[rr][tid] = proj[(row0 + rr) * D3 + 2 * DD + tid];
  __syncthreads();
  float acc[32];
#pragma unroll
  for (int r = 0; r < 32; ++r) acc[r] = 0.f;
  for (int d = 0; d < DD; ++d) {
    const float w = Wout[tid * DD + d];
#pragma unroll
    for (int r = 0; r < 32; ++r) acc[r] += w * s_L[r][d];
  }
  for (int r = 0; r < 32; ++r)
    proj[(row0 + r) * D3 + 2 * DD + tid] = acc[r];
}

// ---- E12 = emb @ Wstep; E1 half gets +fixedc folded in ----------------------
__global__ __launch_bounds__(256) void k_ectx(const float* __restrict__ emb,
                                              const float* __restrict__ Wstep,
                                              const float* __restrict__ fixedc,
                                              float* __restrict__ E12) {
  const size_t row0 = (size_t)blockIdx.x * 32;
  __shared__ float s_A[32][DD];
  const int tid = threadIdx.x;  // 256
  for (int t = tid; t < 32 * DD; t += 256)
    s_A[t >> 7][t & 127] = emb[row0 * DD + t];
  __syncthreads();
  float acc[32];
#pragma unroll
  for (int r = 0; r < 32; ++r) acc[r] = 0.f;
  const int c = tid;
  const int b = (int)(row0 >> 9);  // 512 rows per batch
  const float* wp = (c < DD) ? (Wstep + c) : (Wstep + DD * DD + (c - DD));
  for (int k = 0; k < DD; ++k) {
    float w = wp[(size_t)k * DD];
#pragma unroll
    for (int r = 0; r < 32; ++r) acc[r] += s_A[r][k] * w;
  }
  const float fc = (c < DD) ? fixedc[b * DD + c] : 0.f;
  for (int r = 0; r < 32; ++r) E12[(row0 + r) * 256 + c] = acc[r] + fc;
}

#define DOT16(q, F)                                                           \
  (q[0] * F[0].x + q[1] * F[0].y + q[2] * F[0].z + q[3] * F[0].w +            \
   q[4] * F[1].x + q[5] * F[1].y + q[6] * F[1].z + q[7] * F[1].w +            \
   q[8] * F[2].x + q[9] * F[2].y + q[10] * F[2].z + q[11] * F[2].w +          \
   q[12] * F[3].x + q[13] * F[3].y + q[14] * F[3].z + q[15] * F[3].w)

// Relaxed barrier (r13-proven): drain LDS ops only; global loads stay in
// flight across the barrier (avoids the vmcnt(0) drain __syncthreads emits).
__device__ __forceinline__ void barrier_rlx() {
  asm volatile("s_waitcnt lgkmcnt(0)" ::: "memory");
  __builtin_amdgcn_s_barrier();
  asm volatile("" ::: "memory");
}

// ---- persistent greedy decode: one block per batch, 512 threads -------------
// 512 thr = 8 waves -> register class up to 256 VGPR (the 1024-thr shape was
// stuck at 64 and spilled any batched-load schedule: r4/r7/r8/r10). Now the
// K+V phase batches 4 rows' K+V fragments concurrently (128 regs live): 2
// exposed LLC round trips per step instead of 4. 8 slots/thread (r in [0,64)).
// L' cache for positions 0..255 in LDS, lane-linear [k][q][tid] (conflict-
// free b128). Slots 4-7 L' batch-issued before B1, held across relaxed
// barriers. Shuffle reductions pipelined across slots.
__global__ __launch_bounds__(512, 1) void k_decode(
    const float* __restrict__ emb, const float* __restrict__ proj,
    const float* __restrict__ fixedc, const float* __restrict__ q0,
    const float* __restrict__ E12, const float* __restrict__ Wstep,
    const float* __restrict__ Wph, const int useE, float* __restrict__ out) {
  const int b = blockIdx.x;
  const int tid = threadIdx.x;   // 512
  const int lane = tid & 63;
  const int wave = tid >> 6;     // 0..7
  const int h = tid & 7, r = tid >> 3;  // head, row-group in [0,64)

  __shared__ float4 s_Lpf[4][4][512];  // 128 KB L' cache, [slot][q][tid]
  __shared__ int s_idx[NN];
  __shared__ int s_pos[NN];
  __shared__ unsigned char s_visited[NN];
  __shared__ float s_hacc[8][8][17];  // per-wave per-head acc16 + sum
  __shared__ float s_heads[DD];
  __shared__ float s_logits[NN];
  __shared__ float s_rm[8];
  __shared__ int s_ri[8];
  __shared__ float s_es[8];
  __shared__ float s_q[DD];        // fallback path only
  __shared__ float s_ctx[2 * DD];  // fallback path only
  __shared__ int s_first, s_prev, s_M, s_swap;
  __shared__ float s_ll, s_lzv;

  const float inv_sqrt_d = 0.08838834764831845f;  // 1/sqrt(128)
  const size_t eb = (size_t)b * NN * DD;
  const size_t e2 = (size_t)b * NN * 256;
  const float* projb = proj + (size_t)b * NN * D3;
  float* outp = out + (size_t)b * NN * NN;
  const size_t PI_OFF = (size_t)BATCH * NN * NN;
  const size_t LL_OFF = PI_OFF + (size_t)BATCH * NN;

  s_idx[tid] = tid;
  s_pos[tid] = tid;
  s_visited[tid] = 0;
  if (tid == 0) { s_first = 0; s_prev = 0; s_ll = 0.f; s_M = NN; }
  // init L' cache: position p = r + 64k (identity), entry [k][q][tid]
#pragma unroll
  for (int k = 0; k < 4; ++k) {
    const float4* lp =
        (const float4*)(projb + (size_t)(r + 64 * k) * D3 + 2 * DD + h * 16);
    s_Lpf[k][0][tid] = lp[0];
    s_Lpf[k][1][tid] = lp[1];
    s_Lpf[k][2][tid] = lp[2];
    s_Lpf[k][3][tid] = lp[3];
  }
  __syncthreads();

  for (int i = 0; i < NN; ++i) {
    const int M = s_M;
    const int first = s_first, prev = s_prev;

    // ---- qf: per-thread head fragment of q (E1' includes fixedc) -----------
    float qf[16];
    if (useE) {
      if (i == 0) {
#pragma unroll
        for (int d = 0; d < 4; ++d) {
          const float4 v = *(const float4*)(q0 + b * DD + h * 16 + d * 4);
          qf[d * 4 + 0] = v.x; qf[d * 4 + 1] = v.y;
          qf[d * 4 + 2] = v.z; qf[d * 4 + 3] = v.w;
        }
      } else {
        const float* e1p = E12 + e2 + (size_t)first * 256 + h * 16;
        const float* e2p = E12 + e2 + (size_t)prev * 256 + DD + h * 16;
#pragma unroll
        for (int d = 0; d < 4; ++d) {
          const float4 a = *(const float4*)(e1p + d * 4);
          const float4 c = *(const float4*)(e2p + d * 4);
          qf[d * 4 + 0] = a.x + c.x;
          qf[d * 4 + 1] = a.y + c.y;
          qf[d * 4 + 2] = a.z + c.z;
          qf[d * 4 + 3] = a.w + c.w;
        }
      }
    } else {
      if (tid < 2 * DD) {
        float v;
        if (i == 0)
          v = Wph[tid];
        else
          v = (tid < DD) ? emb[eb + (size_t)first * DD + tid]
                         : emb[eb + (size_t)prev * DD + (tid - DD)];
        s_ctx[tid] = v;
      }
      __syncthreads();
      if (tid < DD) {
        float a = fixedc[b * DD + tid];
        for (int k = 0; k < 2 * DD; ++k) a += s_ctx[k] * Wstep[k * DD + tid];
        s_q[tid] = a;
      }
      __syncthreads();
#pragma unroll
      for (int d = 0; d < 16; ++d) qf[d] = s_q[h * 16 + d];
    }

    // ---- slots ------------------------------------------------------------
    bool act[8];
    int nj[8];
#pragma unroll
    for (int k = 0; k < 8; ++k) {
      const int j = r + 64 * k;
      act[k] = (j < M);
      nj[k] = s_idx[j];
    }

    // ---- KV phase: 2 groups of 4 batched rows (no max shift, r9) ----------
    float s_l = 0.f;
    float acc[16];
#pragma unroll
    for (int d = 0; d < 16; ++d) acc[d] = 0.f;

#define KV_GROUP(K0)                                                          \
    {                                                                         \
      float4 Kf[4][4], Vf[4][4];                                              \
      _Pragma("unroll")                                                       \
      for (int k = 0; k < 4; ++k) {                                           \
        if (act[K0 + k]) {                                                    \
          const float* rp = projb + (size_t)nj[K0 + k] * D3 + h * 16;         \
          const float4* kp = (const float4*)rp;                               \
          Kf[k][0] = kp[0]; Kf[k][1] = kp[1];                                 \
          Kf[k][2] = kp[2]; Kf[k][3] = kp[3];                                 \
          const float4* vp = (const float4*)(rp + DD);                        \
          Vf[k][0] = vp[0]; Vf[k][1] = vp[1];                                 \
          Vf[k][2] = vp[2]; Vf[k][3] = vp[3];                                 \
        }                                                                     \
      }                                                                       \
      _Pragma("unroll")                                                       \
      for (int k = 0; k < 4; ++k) {                                           \
        if (act[K0 + k]) {                                                    \
          const float a = DOT16(qf, Kf[k]);                                   \
          const float p = expf(a * 0.25f);                                    \
          s_l += p;                                                           \
          acc[0] += p * Vf[k][0].x;  acc[1] += p * Vf[k][0].y;                \
          acc[2] += p * Vf[k][0].z;  acc[3] += p * Vf[k][0].w;                \
          acc[4] += p * Vf[k][1].x;  acc[5] += p * Vf[k][1].y;                \
          acc[6] += p * Vf[k][1].z;  acc[7] += p * Vf[k][1].w;                \
          acc[8] += p * Vf[k][2].x;  acc[9] += p * Vf[k][2].y;                \
          acc[10] += p * Vf[k][2].z; acc[11] += p * Vf[k][2].w;               \
          acc[12] += p * Vf[k][3].x; acc[13] += p * Vf[k][3].y;               \
          acc[14] += p * Vf[k][3].z; acc[15] += p * Vf[k][3].w;               \
        }                                                                     \
      }                                                                       \
    }

    KV_GROUP(0);
    if (M > 256) KV_GROUP(4);

    // recursive-halving reduce of acc16 over the 8 lanes sharing head h
    {
      const bool k1 = (lane & 8) == 0;
#pragma unroll
      for (int d = 0; d < 8; ++d) {
        const float send = k1 ? acc[d + 8] : acc[d];
        const float got = __shfl_xor(send, 8);
        acc[d] = (k1 ? acc[d] : acc[d + 8]) + got;
      }
      const bool k2 = (lane & 16) == 0;
#pragma unroll
      for (int d = 0; d < 4; ++d) {
        const float send = k2 ? acc[d + 4] : acc[d];
        const float got = __shfl_xor(send, 16);
        acc[d] = (k2 ? acc[d] : acc[d + 4]) + got;
      }
      const bool k3 = (lane & 32) == 0;
#pragma unroll
      for (int d = 0; d < 2; ++d) {
        const float send = k3 ? acc[d + 2] : acc[d];
        const float got = __shfl_xor(send, 32);
        acc[d] = (k3 ? acc[d] : acc[d + 2]) + got;
      }
    }
    s_l += __shfl_xor(s_l, 8);
    s_l += __shfl_xor(s_l, 16);
    s_l += __shfl_xor(s_l, 32);
    {
      const int dim0 = ((lane & 8) ? 8 : 0) | ((lane & 16) ? 4 : 0) |
                       ((lane & 32) ? 2 : 0);
      s_hacc[wave][h][dim0] = acc[0];
      s_hacc[wave][h][dim0 + 1] = acc[1];
      if (lane < 8) s_hacc[wave][lane][16] = s_l;
    }
    // ---- batch-issue L' for slots 4-7; stays in flight across B1/B2 --------
    float4 Lf[4][4];
    if (M > 256) {
#pragma unroll
      for (int k = 0; k < 4; ++k) {
        if (act[4 + k]) {
          const float4* lp =
              (const float4*)(projb + (size_t)nj[4 + k] * D3 + 2 * DD + h * 16);
          Lf[k][0] = lp[0]; Lf[k][1] = lp[1];
          Lf[k][2] = lp[2]; Lf[k][3] = lp[3];
        }
      }
    }
    barrier_rlx();  // B1: s_hacc ready; Lf in flight

    // ---- [B1,B2): heads (tid<128) + visited-fill (all threads) -------------
    if (tid < DD) {
      const int hh = tid >> 4, dh = tid & 15;
      float num = 0.f, den = 0.f;
#pragma unroll
      for (int w = 0; w < 8; ++w) {
        num += s_hacc[w][hh][dh];
        den += s_hacc[w][hh][16];
      }
      s_heads[tid] = num / den;
    }
    if (s_visited[tid]) s_logits[tid] = NEGV;
    barrier_rlx();  // B2: s_heads ready; Lf still in flight

    // ---- [B2,B3): logits — slots 0-3 from LDS, 4-7 from in-flight regs -----
    float gf[16];
#pragma unroll
    for (int d = 0; d < 16; ++d) gf[d] = s_heads[h * 16 + d];
    float aa[8];
#pragma unroll
    for (int k = 0; k < 4; ++k) {
      if (act[k]) {
        float4 LA[4];
        LA[0] = s_Lpf[k][0][tid];
        LA[1] = s_Lpf[k][1][tid];
        LA[2] = s_Lpf[k][2][tid];
        LA[3] = s_Lpf[k][3][tid];
        aa[k] = DOT16(gf, LA);
      }
    }
    if (M > 256) {
#pragma unroll
      for (int k = 0; k < 4; ++k)
        if (act[4 + k]) aa[4 + k] = DOT16(gf, Lf[k]);
    }
    // pipelined 3-level shuffle reduce across all slots (uniform in 8-lane
    // row-groups: all 8 lanes of a group share r -> same act[k])
#pragma unroll
    for (int off = 1; off <= 4; off <<= 1) {
#pragma unroll
      for (int k = 0; k < 8; ++k)
        if (act[k]) aa[k] += __shfl_xor(aa[k], off);
    }
    float av = NEGINF;
    int ai = 0x7FFFFFFF;
    float asum = 0.f;
    if (h == 0) {
#pragma unroll
      for (int k = 0; k < 8; ++k) {
        if (act[k]) {
          const float lg = 10.0f * tanhf(aa[k] * inv_sqrt_d);
          s_logits[nj[k]] = lg;
          asum += expf(lg);  // |logits|<=10: no max shift needed
          if (lg > av || (lg == av && nj[k] < ai)) { av = lg; ai = nj[k]; }
        }
      }
    }
#pragma unroll
    for (int off = 1; off <= 32; off <<= 1) {
      const float ov = __shfl_xor(av, off);
      const int oi = __shfl_xor(ai, off);
      asum += __shfl_xor(asum, off);
      if (ov > av || (ov == av && oi < ai)) { av = ov; ai = oi; }
    }
    if (lane == 0) { s_rm[wave] = av; s_ri[wave] = ai; s_es[wave] = asum; }
    barrier_rlx();  // B3: s_logits + wave triples ready

    // ---- [B3,B4): wave0-only combine + state update ------------------------
    if (wave == 0) {
      float cv = (lane < 8) ? s_rm[lane] : NEGINF;
      int ci = (lane < 8) ? s_ri[lane] : 0x7FFFFFFF;
      float cs = (lane < 8) ? s_es[lane] : 0.f;
#pragma unroll
      for (int off = 1; off <= 4; off <<= 1) {
        const float ov = __shfl_xor(cv, off);
        const int oi = __shfl_xor(ci, off);
        cs += __shfl_xor(cs, off);
        if (ov > cv || (ov == cv && oi < ci)) { cv = ov; ci = oi; }
      }
      if (lane == 0) {
        const float lzv = logf(cs);
        const int sel = ci;
        s_lzv = lzv;
        s_ll += cv - lzv;  // cv == logits[sel]
        s_visited[sel] = 1;
        if (i == 0) s_first = sel;
        s_prev = sel;
        out[PI_OFF + (size_t)b * NN + i] = (float)sel;
        const int p = s_pos[sel];
        const int last = s_idx[M - 1];
        s_idx[p] = last;
        s_pos[last] = p;
        s_idx[M - 1] = sel;
        s_pos[sel] = M - 1;
        s_M = M - 1;
        s_swap = p;  // position whose content changed (now holds `last`)
      }
    }
    barrier_rlx();  // B4: state + lz visible

    // ---- refresh the one changed cache position ----------------------------
    {
      const int sp = s_swap;
      if (sp < 256 && r == (sp & 63)) {
        const int sl = sp >> 6;
        const int nr = s_idx[sp];
        const float4* lp =
            (const float4*)(projb + (size_t)nr * D3 + 2 * DD + h * 16);
        s_Lpf[sl][0][tid] = lp[0];
        s_Lpf[sl][1][tid] = lp[1];
        s_Lpf[sl][2][tid] = lp[2];
        s_Lpf[sl][3][tid] = lp[3];
      }
    }
    const float lz = s_lzv;
    outp[(size_t)i * NN + tid] = s_logits[tid] - lz;
  }
  if (tid == 0) out[LL_OFF + b] = s_ll;
}

extern "C" void kernel_launch(void* const* d_in, const int* in_sizes, int n_in,
                              void* d_out, int out_size, void* d_ws,
                              size_t ws_size, hipStream_t stream) {
  const float* emb = (const float*)d_in[0];    // [B,N,D]
  const float* Wnp = (const float*)d_in[1];    // [D,3D]
  const float* Wf = (const float*)d_in[2];     // [D,D]
  const float* Wstep = (const float*)d_in[3];  // [2D,D]
  const float* Wout = (const float*)d_in[4];   // [D,D]
  const float* Wph = (const float*)d_in[5];    // [2D]
  float* out = (float*)d_out;

  const size_t projN = (size_t)BATCH * NN * D3;
  const size_t eN = (size_t)BATCH * NN * 256;
  const size_t need_full = (projN + eN + 2 * (size_t)BATCH * DD) * 4;

  float* proj = (float*)d_ws;
  float* E12 = proj + projN;
  const int useE = (ws_size >= need_full) ? 1 : 0;
  float* fixedc = useE ? (E12 + eN) : (proj + projN);
  float* q0 = fixedc + (size_t)BATCH * DD;

  k_fixed<<<BATCH, 256, 0, stream>>>(emb, Wf, Wstep, Wph, fixedc, q0);
  k_proj<<<(BATCH * NN) / 32, 384, 0, stream>>>(emb, Wnp, proj);
  k_lp<<<(BATCH * NN) / 32, 128, 0, stream>>>(proj, Wout);
  if (useE) k_ectx<<<(BATCH * NN) / 32, 256, 0, stream>>>(emb, Wstep, fixedc, E12);
  k_decode<<<BATCH, 512, 0, stream>>>(emb, proj, fixedc, q0,
                                      useE ? E12 : nullptr, Wstep, Wph, useE,
                                      out);
}